// Round 10
// baseline (130.258 us; speedup 1.0000x reference)
//
#include <hip/hip_runtime.h>

typedef short short8 __attribute__((ext_vector_type(8)));
typedef float f32x4 __attribute__((ext_vector_type(4)));

#define BN_EPS 1e-5f
#define CUT_THRESH 1e-3f

// ws layout (bytes):
//   [0, 18432)        wbf  (9216 bf16, [kk][co][ci] ci-octet ^ ((co>>1)&3) swizzle)
//   [18432, 18688)    coef (64 f32: scl[0:32], sft[32:64])
//   [18688, +2359296) part (1024 planes x 576 wave-tile partials f32)
#define WS_COEF 18432
#define WS_PART 18688

__device__ __forceinline__ unsigned short f2bf(float f) {
  unsigned u = __float_as_uint(f);
  u += 0x7FFFu + ((u >> 16) & 1u);  // RNE (prep only)
  return (unsigned short)(u >> 16);
}

// One-time weight conversion + BN coefficient fusion.
__global__ void prep_kernel(const float* __restrict__ wgt,
                            const float* __restrict__ bias,
                            const float* __restrict__ gamma,
                            const float* __restrict__ beta,
                            const float* __restrict__ rmean,
                            const float* __restrict__ rvar,
                            unsigned short* __restrict__ wbf,
                            float* __restrict__ coef) {
  int tid = blockIdx.x * 256 + threadIdx.x;
  if (tid < 9216) {
    int co = tid / 288;  // wgt is OIHW
    int rem = tid - co * 288;
    int ci = rem / 9;
    int kk = rem - ci * 9;
    int oct = ((ci >> 3) ^ ((co >> 1) & 3)) << 3;
    wbf[(kk * 32 + co) * 32 + oct + (ci & 7)] = f2bf(wgt[tid]);
  }
  if (tid < 32) {
    float s = gamma[tid] * rsqrtf(rvar[tid] + BN_EPS);
    coef[tid] = s;
    coef[32 + tid] = (bias[tid] - rmean[tid]) * s + beta[tid];
  }
}

// Wave-INDEPENDENT implicit-GEMM conv 3x3 + BN + ReLU.
// Each wave owns a 4x16 px x 32 co tile + a private 6.75 KB LDS slice.
// NO __syncthreads anywhere: same-wave LDS RAW is ordered by lgkmcnt (compiler).
__global__ __launch_bounds__(256, 4) void conv_bn_relu_kernel(
    const float* __restrict__ x,
    const unsigned short* __restrict__ wbf,
    const float* __restrict__ coef,
    float* __restrict__ out,
    float* __restrict__ part) {
  // per-wave x tile: [h:6][w:18][ci-octet swz:4][8] bf16 = 6912 B; 4 waves = 27648 B
  __shared__ unsigned short lx[4][6 * 18 * 32];

  int tid = threadIdx.x;
  int wv = tid >> 6;
  int lane = tid & 63;
  int l15 = lane & 15;
  int lg = lane >> 4;

  // wave-tile id, XCD-bijective over blocks (4608 = 8*576)
  int wtile = (((blockIdx.x & 7) * 576 + (blockIdx.x >> 3)) << 2) + wv;
  int b = wtile / 576;
  int t = wtile - b * 576;      // 0..575
  int tr = t / 12, tc = t - tr * 12;
  int r0 = tr * 4, c0 = tc * 16;

  const float* xb = x + b * (32 * 192 * 192);
  unsigned short* lxw = &lx[wv][0];

  int m48 = (lane >= 48) ? lane - 48 : lane;

  // ---- staging: 432 octet-tasks/wave, 7 lane-rounds, 2 issue/pack phases ----
  // task id -> g = id&3 (ci octet), p = id>>2 = h*18 + wl (6x18 halo tile)
  float fv[4][8];
  int lofs[4];
  int okm[4];

#pragma unroll 1
  for (int ph = 0; ph < 2; ++ph) {
    const int nr = ph ? 3 : 4;
    // phase issue: up to 32 independent scalar loads
#pragma unroll
    for (int r = 0; r < 4; ++r) {
      if (r >= nr) break;
      int rr = ph ? 4 + r : r;
      int id = (rr < 6) ? (rr * 64 + lane) : (384 + m48);
      int g = id & 3;
      int p = id >> 2;  // 0..107
      int h = p / 18;
      int wl = p - h * 18;
      int gh = r0 - 1 + h, gw = c0 - 1 + wl;
      okm[r] = (((unsigned)gh < 192u) && ((unsigned)gw < 192u)) ? -1 : 0;
      int ghc = min(max(gh, 0), 191);
      int gwc = min(max(gw, 0), 191);
      const float* src = xb + (g * 8) * 36864 + ghc * 192 + gwc;
#pragma unroll
      for (int j = 0; j < 8; ++j) fv[r][j] = src[j * 36864];
      lofs[r] = p * 32 + ((g ^ ((wl >> 1) & 3)) << 3);
    }
    __builtin_amdgcn_sched_barrier(0);  // keep packs from sinking into issue
    // phase pack: round-half-up bf16 + swizzled ds_write_b128
#pragma unroll
    for (int r = 0; r < 4; ++r) {
      if (r >= nr) break;
      unsigned pk[4];
#pragma unroll
      for (int q = 0; q < 4; ++q) {
        float f0 = okm[r] ? fv[r][2 * q] : 0.f;
        float f1 = okm[r] ? fv[r][2 * q + 1] : 0.f;
        unsigned a = __float_as_uint(f0) + 0x8000u;
        unsigned c = __float_as_uint(f1) + 0x8000u;
        pk[q] = (a >> 16) | (c & 0xffff0000u);
      }
      short8 v;
      reinterpret_cast<unsigned*>(&v)[0] = pk[0];
      reinterpret_cast<unsigned*>(&v)[1] = pk[1];
      reinterpret_cast<unsigned*>(&v)[2] = pk[2];
      reinterpret_cast<unsigned*>(&v)[3] = pk[3];
      *reinterpret_cast<short8*>(&lxw[lofs[r]]) = v;
    }
  }

  // ---- fused BN coefficients ----
  f32x4 scl[2], sft[2];
#pragma unroll
  for (int m = 0; m < 2; ++m) {
    scl[m] = *reinterpret_cast<const f32x4*>(coef + m * 16 + lg * 4);
    sft[m] = *reinterpret_cast<const f32x4*>(coef + 32 + m * 16 + lg * 4);
  }

  // B offsets within a row (static-indexed, rule #20 safe)
  int aswz = (lg ^ ((l15 >> 1) & 3)) << 3;
  int off0[3];
#pragma unroll
  for (int kw = 0; kw < 3; ++kw) {
    int wl = kw + l15;  // 0..17 local col
    off0[kw] = wl * 32 + ((lg ^ ((wl >> 1) & 3)) << 3);
  }
  const unsigned short* aBase = wbf + (l15 << 5) + aswz;

  f32x4 acc[2][4] = {};

  // ---- MFMA loop: no barrier needed (own-wave LDS, lgkmcnt by compiler).
  //      kh not unrolled -> at most 6 A-loads live; latency hidden by 16
  //      independent waves/CU. ----
#pragma unroll 1
  for (int kh = 0; kh < 3; ++kh) {
    const unsigned short* aRow = aBase + kh * 3072;
    int rowOfs = kh * 576;  // 18*32 shorts per tile row
#pragma unroll
    for (int kw = 0; kw < 3; ++kw) {
      short8 A0 = *reinterpret_cast<const short8*>(aRow + kw * 1024);
      short8 A1 = *reinterpret_cast<const short8*>(aRow + kw * 1024 + 512);
#pragma unroll
      for (int n = 0; n < 4; ++n) {
        short8 Bf = *reinterpret_cast<const short8*>(
            &lxw[rowOfs + n * 576 + off0[kw]]);
        acc[0][n] = __builtin_amdgcn_mfma_f32_16x16x32_bf16(A0, Bf, acc[0][n], 0, 0, 0);
        acc[1][n] = __builtin_amdgcn_mfma_f32_16x16x32_bf16(A1, Bf, acc[1][n], 0, 0, 0);
      }
    }
  }

  // ---- epilogue: BN + ReLU, store, per-plane max partials (no atomics) ----
  const int HW = 192 * 192;
  float* ob = out + b * 32 * HW;
  float pmax[2][4];
#pragma unroll
  for (int m = 0; m < 2; ++m)
#pragma unroll
    for (int j = 0; j < 4; ++j) pmax[m][j] = 0.f;

#pragma unroll
  for (int m = 0; m < 2; ++m)
#pragma unroll
    for (int n = 0; n < 4; ++n) {
      int gr = r0 + n;          // n indexes the 4 tile rows
      int gc = c0 + l15;
#pragma unroll
      for (int j = 0; j < 4; ++j) {
        int co = m * 16 + lg * 4 + j;  // D row = (lane>>4)*4 + reg (m89-verified)
        float v = fmaxf(acc[m][n][j] * scl[m][j] + sft[m][j], 0.f);
        ob[co * HW + gr * 192 + gc] = v;
        pmax[m][j] = fmaxf(pmax[m][j], v);
      }
    }

  // 16-lane reduce; l15==0 lanes write 8 per-wave partials -> unique slots
#pragma unroll
  for (int m = 0; m < 2; ++m)
#pragma unroll
    for (int j = 0; j < 4; ++j) {
      float v = pmax[m][j];
      v = fmaxf(v, __shfl_xor(v, 1, 16));
      v = fmaxf(v, __shfl_xor(v, 2, 16));
      v = fmaxf(v, __shfl_xor(v, 4, 16));
      v = fmaxf(v, __shfl_xor(v, 8, 16));
      if (l15 == 0) {
        int co = m * 16 + lg * 4 + j;
        part[((size_t)b * 32 + co) * 576 + t] = v;
      }
    }
}

// Per (b,co) plane: reduce 576 contiguous partials; zero plane if < thresh.
__global__ __launch_bounds__(256) void cut_kernel(float* __restrict__ out,
                                                  const float* __restrict__ part) {
  __shared__ float r4[4];
  int p = blockIdx.x;  // b*32 + co
  const float* pp = part + (size_t)p * 576;
  float m = 0.f;
  for (int i = threadIdx.x; i < 576; i += 256) m = fmaxf(m, pp[i]);
#pragma unroll
  for (int k = 1; k < 64; k <<= 1) m = fmaxf(m, __shfl_xor(m, k, 64));
  if ((threadIdx.x & 63) == 0) r4[threadIdx.x >> 6] = m;
  __syncthreads();
  m = fmaxf(fmaxf(r4[0], r4[1]), fmaxf(r4[2], r4[3]));
  if (m >= CUT_THRESH) return;  // uniform; never fires on this data
  float* base = out + (size_t)p * 36864;
  for (int i = threadIdx.x; i < 36864; i += 256) base[i] = 0.f;
}

extern "C" void kernel_launch(void* const* d_in, const int* in_sizes, int n_in,
                              void* d_out, int out_size, void* d_ws, size_t ws_size,
                              hipStream_t stream) {
  const float* x     = (const float*)d_in[0];
  const float* wgt   = (const float*)d_in[1];
  const float* bias  = (const float*)d_in[2];
  const float* gamma = (const float*)d_in[3];
  const float* beta  = (const float*)d_in[4];
  const float* rmean = (const float*)d_in[5];
  const float* rvar  = (const float*)d_in[6];
  float* out = (float*)d_out;

  unsigned short* wbf  = (unsigned short*)d_ws;
  float*          coef = (float*)((char*)d_ws + WS_COEF);
  float*          part = (float*)((char*)d_ws + WS_PART);

  prep_kernel<<<36, 256, 0, stream>>>(wgt, bias, gamma, beta, rmean, rvar, wbf, coef);
  conv_bn_relu_kernel<<<4608, 256, 0, stream>>>(x, wbf, coef, out, part);
  cut_kernel<<<1024, 256, 0, stream>>>(out, part);
}

// Round 11
// 76.697 us; speedup vs baseline: 1.6983x; 1.6983x over previous
//
#include <hip/hip_runtime.h>

typedef short short8 __attribute__((ext_vector_type(8)));
typedef float f32x4 __attribute__((ext_vector_type(4)));

#define BN_EPS 1e-5f
#define CUT_THRESH 1e-3f

// ws layout (bytes):
//   [0, 18432)        wbf  (9216 bf16, [kk][co][ci] ci-octet ^ ((co>>1)&3) swizzle)
//   [18432, 18688)    coef (64 f32: scl[0:32], sft[32:64])
//   [18688, +2359296) part (1024 planes x 576 wave-partials f32, contiguous/plane)
#define WS_COEF 18432
#define WS_PART 18688

__device__ __forceinline__ unsigned short f2bf(float f) {
  unsigned u = __float_as_uint(f);
  u += 0x7FFFu + ((u >> 16) & 1u);  // RNE (prep only)
  return (unsigned short)(u >> 16);
}

__device__ __forceinline__ void gload_lds16(const void* g, void* l) {
  __builtin_amdgcn_global_load_lds(
      (const __attribute__((address_space(1))) unsigned int*)g,
      (__attribute__((address_space(3))) unsigned int*)l, 16, 0, 0);
}

// One-time weight conversion + BN coefficient fusion.
__global__ void prep_kernel(const float* __restrict__ wgt,
                            const float* __restrict__ bias,
                            const float* __restrict__ gamma,
                            const float* __restrict__ beta,
                            const float* __restrict__ rmean,
                            const float* __restrict__ rvar,
                            unsigned short* __restrict__ wbf,
                            float* __restrict__ coef) {
  int tid = blockIdx.x * 256 + threadIdx.x;
  if (tid < 9216) {
    int co = tid / 288;  // wgt is OIHW
    int rem = tid - co * 288;
    int ci = rem / 9;
    int kk = rem - ci * 9;
    int oct = ((ci >> 3) ^ ((co >> 1) & 3)) << 3;
    wbf[(kk * 32 + co) * 32 + oct + (ci & 7)] = f2bf(wgt[tid]);
  }
  if (tid < 32) {
    float s = gamma[tid] * rsqrtf(rvar[tid] + BN_EPS);
    coef[tid] = s;
    coef[32 + tid] = (bias[tid] - rmean[tid]) * s + beta[tid];
  }
}

// Implicit-GEMM conv 3x3 + BN + ReLU; tile 8x32 px x 32 co per 256-thr block.
// Staging: phase-1 issues ALL 48 x-loads (max MLP), phase-2 converts+ds_writes.
// Output stores are NON-TEMPORAL: they stream to HBM without evicting x from
// the 256MB L3 (x + out = 302MB > L3; write-allocation was re-fetching ~74MB
// of x per pass).
__global__ __launch_bounds__(256, 3) void conv_bn_relu_kernel(
    const float* __restrict__ x,
    const unsigned short* __restrict__ wbf,
    const float* __restrict__ coef,
    float* __restrict__ out,
    float* __restrict__ part) {
  __shared__ unsigned short lx[10 * 34 * 32];  // 21760 B
  __shared__ unsigned short lw[9 * 32 * 32];   // 18432 B -> 40192 B, 3 blk/CU

  int bid = blockIdx.x;
  int orig = (bid & 7) * 576 + (bid >> 3);  // XCD-bijective: 4608 = 8*576
  int b = orig / 144;
  int t = orig - b * 144;
  int tr = t / 6, tc = t - tr * 6;
  int r0 = tr * 8, c0 = tc * 32;
  int tid = threadIdx.x;

  // ---- weights: 1152 x 16B DMA chunks (drained by the barrier) ----
  {
    const short8* wsrc = reinterpret_cast<const short8*>(wbf);
    short8* wdst = reinterpret_cast<short8*>(lw);
#pragma unroll
    for (int r = 0; r < 4; ++r) gload_lds16(wsrc + r * 256 + tid, wdst + r * 256 + tid);
    if (tid < 128) gload_lds16(wsrc + 1024 + tid, wdst + 1024 + tid);
  }

  // ---- x staging: 1360 octet-tasks; each thread 6 slots (slot 5 wraps
  //      ids 1280..1359, benign same-data duplication) ----
  const float* xb = x + b * (32 * 192 * 192);
  int m80 = tid;
  m80 = (m80 >= 160) ? m80 - 160 : m80;
  m80 = (m80 >= 80) ? m80 - 80 : m80;

  float fv[6][8];
  int lofs[6];
  int okm[6];
  // phase 1: compute addresses, issue all 48 independent loads
#pragma unroll
  for (int r = 0; r < 6; ++r) {
    int id = (r < 5) ? (r * 256 + tid) : (1280 + m80);
    int g = id & 3;
    int p = id >> 2;  // h*34 + w
    int h = p / 34;
    int w = p - h * 34;
    int gh = r0 - 1 + h, gw = c0 - 1 + w;
    okm[r] = (((unsigned)gh < 192u) && ((unsigned)gw < 192u)) ? -1 : 0;
    int ghc = min(max(gh, 0), 191);
    int gwc = min(max(gw, 0), 191);
    const float* src = xb + (g * 8) * 36864 + ghc * 192 + gwc;
#pragma unroll
    for (int j = 0; j < 8; ++j) fv[r][j] = src[j * 36864];  // 48 loads in flight
    lofs[r] = p * 32 + ((g ^ ((w >> 1) & 3)) << 3);
  }
  __builtin_amdgcn_sched_barrier(0);  // keep converts from sinking into load issue

  // phase 2: convert (round-half-up) + swizzled ds_write_b128
#pragma unroll
  for (int r = 0; r < 6; ++r) {
    unsigned pk[4];
#pragma unroll
    for (int q = 0; q < 4; ++q) {
      float f0 = okm[r] ? fv[r][2 * q] : 0.f;
      float f1 = okm[r] ? fv[r][2 * q + 1] : 0.f;
      unsigned a = __float_as_uint(f0) + 0x8000u;
      unsigned c = __float_as_uint(f1) + 0x8000u;
      pk[q] = (a >> 16) | (c & 0xffff0000u);
    }
    short8 v;
    reinterpret_cast<unsigned*>(&v)[0] = pk[0];
    reinterpret_cast<unsigned*>(&v)[1] = pk[1];
    reinterpret_cast<unsigned*>(&v)[2] = pk[2];
    reinterpret_cast<unsigned*>(&v)[3] = pk[3];
    *reinterpret_cast<short8*>(&lx[lofs[r]]) = v;
  }

  int lane = tid & 63;
  int wv = tid >> 6;  // wave -> rows 2wv, 2wv+1
  int l15 = lane & 15;
  int lg = lane >> 4;

  f32x4 scl[2], sft[2];
#pragma unroll
  for (int m = 0; m < 2; ++m) {
    scl[m] = *reinterpret_cast<const f32x4*>(coef + m * 16 + lg * 4);
    sft[m] = *reinterpret_cast<const f32x4*>(coef + 32 + m * 16 + lg * 4);
  }

  __syncthreads();

  int aswz = (lg ^ ((l15 >> 1) & 3)) << 3;
  f32x4 acc[2][4] = {};

  // ---- MFMA loop: A-fragments from LDS per tap; B from swizzled lx ----
#pragma unroll
  for (int s = 0; s < 9; ++s) {
    const int kh = s / 3, kw = s - kh * 3;
    short8 A0 = *reinterpret_cast<const short8*>(&lw[(s * 32 + l15) * 32 + aswz]);
    short8 A1 = *reinterpret_cast<const short8*>(&lw[(s * 32 + 16 + l15) * 32 + aswz]);
#pragma unroll
    for (int n = 0; n < 4; ++n) {
      int hl = 2 * wv + (n >> 1) + kh;
      int wl = ((n & 1) << 4) + l15 + kw;
      short8 Bf = *reinterpret_cast<const short8*>(
          &lx[(hl * 34 + wl) * 32 + ((lg ^ ((wl >> 1) & 3)) << 3)]);
      acc[0][n] = __builtin_amdgcn_mfma_f32_16x16x32_bf16(A0, Bf, acc[0][n], 0, 0, 0);
      acc[1][n] = __builtin_amdgcn_mfma_f32_16x16x32_bf16(A1, Bf, acc[1][n], 0, 0, 0);
    }
  }

  // ---- epilogue: BN + ReLU, NON-TEMPORAL stores, per-plane max partials ----
  const int HW = 192 * 192;
  float* ob = out + b * 32 * HW;
  float pmax[2][4];
#pragma unroll
  for (int m = 0; m < 2; ++m)
#pragma unroll
    for (int j = 0; j < 4; ++j) pmax[m][j] = 0.f;

#pragma unroll
  for (int m = 0; m < 2; ++m)
#pragma unroll
    for (int n = 0; n < 4; ++n) {
      int gr = r0 + 2 * wv + (n >> 1);
      int gc = c0 + ((n & 1) << 4) + l15;
#pragma unroll
      for (int j = 0; j < 4; ++j) {
        int co = m * 16 + lg * 4 + j;  // D row = (lane>>4)*4 + reg (m89-verified)
        float v = fmaxf(acc[m][n][j] * scl[m][j] + sft[m][j], 0.f);
        __builtin_nontemporal_store(v, &ob[co * HW + gr * 192 + gc]);
        pmax[m][j] = fmaxf(pmax[m][j], v);
      }
    }

  // 16-lane reduce; l15==0 lanes write 8 per-wave partials -> unique slots
#pragma unroll
  for (int m = 0; m < 2; ++m)
#pragma unroll
    for (int j = 0; j < 4; ++j) {
      float v = pmax[m][j];
      v = fmaxf(v, __shfl_xor(v, 1, 16));
      v = fmaxf(v, __shfl_xor(v, 2, 16));
      v = fmaxf(v, __shfl_xor(v, 4, 16));
      v = fmaxf(v, __shfl_xor(v, 8, 16));
      if (l15 == 0) {
        int co = m * 16 + lg * 4 + j;
        __builtin_nontemporal_store(v, &part[((size_t)b * 32 + co) * 576 + t * 4 + wv]);
      }
    }
}

// Per (b,co) plane: reduce 576 contiguous partials; zero plane if < thresh.
__global__ __launch_bounds__(256) void cut_kernel(float* __restrict__ out,
                                                  const float* __restrict__ part) {
  __shared__ float r4[4];
  int p = blockIdx.x;  // b*32 + co
  const float* pp = part + (size_t)p * 576;
  float m = 0.f;
  for (int i = threadIdx.x; i < 576; i += 256) m = fmaxf(m, pp[i]);
#pragma unroll
  for (int k = 1; k < 64; k <<= 1) m = fmaxf(m, __shfl_xor(m, k, 64));
  if ((threadIdx.x & 63) == 0) r4[threadIdx.x >> 6] = m;
  __syncthreads();
  m = fmaxf(fmaxf(r4[0], r4[1]), fmaxf(r4[2], r4[3]));
  if (m >= CUT_THRESH) return;  // uniform; never fires on this data
  float* base = out + (size_t)p * 36864;
  for (int i = threadIdx.x; i < 36864; i += 256) base[i] = 0.f;
}

extern "C" void kernel_launch(void* const* d_in, const int* in_sizes, int n_in,
                              void* d_out, int out_size, void* d_ws, size_t ws_size,
                              hipStream_t stream) {
  const float* x     = (const float*)d_in[0];
  const float* wgt   = (const float*)d_in[1];
  const float* bias  = (const float*)d_in[2];
  const float* gamma = (const float*)d_in[3];
  const float* beta  = (const float*)d_in[4];
  const float* rmean = (const float*)d_in[5];
  const float* rvar  = (const float*)d_in[6];
  float* out = (float*)d_out;

  unsigned short* wbf  = (unsigned short*)d_ws;
  float*          coef = (float*)((char*)d_ws + WS_COEF);
  float*          part = (float*)((char*)d_ws + WS_PART);

  prep_kernel<<<36, 256, 0, stream>>>(wgt, bias, gamma, beta, rmean, rvar, wbf, coef);
  conv_bn_relu_kernel<<<4608, 256, 0, stream>>>(x, wbf, coef, out, part);
  cut_kernel<<<1024, 256, 0, stream>>>(out, part);
}